// Round 1
// 438.768 us; speedup vs baseline: 1.1807x; 1.1807x over previous
//
#include <hip/hip_runtime.h>
#include <math.h>

// Problem: B=64, N_total=1029, D=768, r=64, E=4, TOPK=1.
// M_TOT = 65856 tokens (1029 blocks of 64); MoE tokens = 65536.
//
// All GEMMs on the matrix pipe: mfma_f32_16x16x32_bf16 with bf16x3
// error-compensated split (hi=bit-truncate, lo=truncate(residual)):
//   a*b ~= ah*bh + ah*bl + al*bh   (dropped al*bl + eps <= ~2^-15 rel)
// A/B staged in LDS as [row][64k] bf16, 128B rows, 16B-chunk XOR swizzle
// (byte ^= (row&7)<<4) -> minimal (8 lanes / bank-quad) on both ds_write_b128
// and ds_read_b128. k-slot placement identical for A and B fragments, so the
// result is invariant to the HW's internal k ordering.

#define GELU(v) (0.5f*(v)*(1.0f + erff((v)*0.70710678118654752440f)))

typedef __attribute__((ext_vector_type(8))) short bf16x8;
typedef __attribute__((ext_vector_type(4))) float f32x4;

#define MFMA(a,b,c) __builtin_amdgcn_mfma_f32_16x16x32_bf16((a),(b),(c),0,0,0)

__device__ __forceinline__ unsigned pk_hi(float a, float b) {
  // pack bf16(a) in low short, bf16(b) in high short (bit truncation)
  return (__float_as_uint(a) >> 16) | (__float_as_uint(b) & 0xFFFF0000u);
}
__device__ __forceinline__ float f_lo(float a) {
  return a - __uint_as_float(__float_as_uint(a) & 0xFFFF0000u);
}
// byte offset of element (row, kbyte) in a [rows][64] bf16 tile, swizzled
__device__ __forceinline__ int swz(int row, int kbyte) {
  return row*128 + (kbyte ^ ((row & 7) << 4));
}
__device__ __forceinline__ void split_store(char* hiB, char* loB, int row, int kg,
                                            float4 f0, float4 f1) {
  uint4 hv, lv;
  hv.x = pk_hi(f0.x, f0.y); hv.y = pk_hi(f0.z, f0.w);
  hv.z = pk_hi(f1.x, f1.y); hv.w = pk_hi(f1.z, f1.w);
  lv.x = pk_hi(f_lo(f0.x), f_lo(f0.y)); lv.y = pk_hi(f_lo(f0.z), f_lo(f0.w));
  lv.z = pk_hi(f_lo(f1.x), f_lo(f1.y)); lv.w = pk_hi(f_lo(f1.z), f_lo(f1.w));
  int off = swz(row, kg << 4);
  *(uint4*)(hiB + off) = hv;
  *(uint4*)(loB + off) = lv;
}
__device__ __forceinline__ bf16x8 frag_ld(const char* b, int row, int kbyte) {
  return *(const bf16x8*)(b + swz(row, kbyte));
}

// ---------------------------------------------------------------------------
// Kernel 1: h = gelu(x . Wd^T)   M=65856, N=64, K=768
// Block: 256 thr (4 waves), tile 64 tokens x 64 outputs, K staged in 64-chunks.
// Wave w: D rows 16w..16w+15, 4 n-tiles, acc 4 x f32x4.
// ---------------------------------------------------------------------------
__global__ __launch_bounds__(256) void k1_proj_gelu(
    const float* __restrict__ x, const float* __restrict__ Wd,
    float* __restrict__ h)
{
  __shared__ uint4 AhS[512], AlS[512], BhS[512], BlS[512];   // 8 KB each
  char* Ah = (char*)AhS; char* Al = (char*)AlS;
  char* Bh = (char*)BhS; char* Bl = (char*)BlS;
  const int tid = threadIdx.x;
  const int bm  = blockIdx.x;
  const int wv = tid >> 6, l = tid & 63;
  const int lg = l >> 4, lr = l & 15;
  const float* xblk = x + (size_t)bm * (64*768);

  f32x4 acc[4];
  #pragma unroll
  for (int i = 0; i < 4; ++i)
    #pragma unroll
    for (int j = 0; j < 4; ++j) acc[i][j] = 0.f;

  for (int kt = 0; kt < 768; kt += 64) {
    #pragma unroll
    for (int it = 0; it < 2; ++it) {
      int li = it*256 + tid;
      int row = li >> 3, kg = li & 7;
      const float* p = xblk + row*768 + kt + kg*8;
      float4 f0 = *(const float4*)p, f1 = *(const float4*)(p+4);
      split_store(Ah, Al, row, kg, f0, f1);
      const float* q = Wd + row*768 + kt + kg*8;      // row = output n here
      float4 g0 = *(const float4*)q, g1 = *(const float4*)(q+4);
      split_store(Bh, Bl, row, kg, g0, g1);
    }
    __syncthreads();
    #pragma unroll
    for (int kc = 0; kc < 2; ++kc) {
      int kb = kc*64 + lg*16;                 // (kc*32 + lg*8) bf16 -> bytes
      bf16x8 ah = frag_ld(Ah, wv*16 + lr, kb);
      bf16x8 al = frag_ld(Al, wv*16 + lr, kb);
      #pragma unroll
      for (int nt = 0; nt < 4; ++nt) {
        bf16x8 bh = frag_ld(Bh, nt*16 + lr, kb);
        bf16x8 bl = frag_ld(Bl, nt*16 + lr, kb);
        acc[nt] = MFMA(ah, bh, acc[nt]);
        acc[nt] = MFMA(ah, bl, acc[nt]);
        acc[nt] = MFMA(al, bh, acc[nt]);
      }
    }
    __syncthreads();
  }
  // C/D: row = wv*16 + lg*4 + r, col = nt*16 + lr   [HW-verified mapping]
  #pragma unroll
  for (int nt = 0; nt < 4; ++nt)
    #pragma unroll
    for (int r = 0; r < 4; ++r) {
      int token = bm*64 + wv*16 + lg*4 + r;
      float v = acc[nt][r];
      h[(size_t)token*64 + nt*16 + lr] = GELU(v);
    }
}

// ---------------------------------------------------------------------------
// Kernel 2: per MoE token top-1 MoE, batched as one GEMM per 64 tokens:
//   D[64 x 272] = t[64 x 64] . B[64 x 272]
//   B cols 0..255 = We[e][s][k] (col = e*64+s), 256..259 = Wg[e][k], rest 0.
//   -> logits in tile 16, expert_all in tiles 0..15. In-register softmax +
//   top-1 select, h[token] += w * (sel + be[e*]).
// ---------------------------------------------------------------------------
__global__ __launch_bounds__(256) void k2_moe(
    const float* __restrict__ Wg, const float* __restrict__ We,
    const float* __restrict__ be, float* __restrict__ h)
{
  __shared__ uint4 AhS[512], AlS[512];       // t tile 64x64
  __shared__ uint4 BhS[2176], BlS[2176];     // 272 rows x 64 k bf16 = 34816 B
  __shared__ float sBe[256];
  char* Ah = (char*)AhS; char* Al = (char*)AlS;
  char* Bh = (char*)BhS; char* Bl = (char*)BlS;
  const int tid = threadIdx.x;
  const int bm  = blockIdx.x;
  const int wv = tid >> 6, l = tid & 63;
  const int lg = l >> 4, lr = l & 15;

  for (int i = tid; i < 2176; i += 256) {
    int col = i >> 3, kg = i & 7;
    float4 f0, f1;
    if (col < 256) {
      const float* p = We + (size_t)col*64 + kg*8;
      f0 = *(const float4*)p; f1 = *(const float4*)(p+4);
    } else if (col < 260) {
      const float* p = Wg + (col-256)*64 + kg*8;
      f0 = *(const float4*)p; f1 = *(const float4*)(p+4);
    } else {
      f0 = make_float4(0.f,0.f,0.f,0.f); f1 = f0;
    }
    split_store(Bh, Bl, col, kg, f0, f1);
  }
  sBe[tid] = be[tid];
  #pragma unroll
  for (int it = 0; it < 2; ++it) {
    int li = it*256 + tid;
    int row = li >> 3, kg = li & 7;
    int mt = bm*64 + row;
    int token = (mt >> 10)*1029 + 5 + (mt & 1023);
    const float* p = h + (size_t)token*64 + kg*8;
    float4 f0 = *(const float4*)p, f1 = *(const float4*)(p+4);
    split_store(Ah, Al, row, kg, f0, f1);
  }
  __syncthreads();

  f32x4 acc[17];
  #pragma unroll
  for (int i = 0; i < 17; ++i)
    #pragma unroll
    for (int j = 0; j < 4; ++j) acc[i][j] = 0.f;

  #pragma unroll
  for (int kc = 0; kc < 2; ++kc) {
    int kb = kc*64 + lg*16;
    bf16x8 ah = frag_ld(Ah, wv*16 + lr, kb);
    bf16x8 al = frag_ld(Al, wv*16 + lr, kb);
    #pragma unroll
    for (int nt = 0; nt < 17; ++nt) {
      bf16x8 bh = frag_ld(Bh, nt*16 + lr, kb);
      bf16x8 bl = frag_ld(Bl, nt*16 + lr, kb);
      acc[nt] = MFMA(ah, bh, acc[nt]);
      acc[nt] = MFMA(ah, bl, acc[nt]);
      acc[nt] = MFMA(al, bh, acc[nt]);
    }
  }

  // selection + combine. Logits for row (lg*4+r) live in lanes (l&48)+e.
  #pragma unroll
  for (int r = 0; r < 4; ++r) {
    float lt = acc[16][r];
    int base = l & 48;
    float l0 = __shfl(lt, base + 0);
    float l1 = __shfl(lt, base + 1);
    float l2 = __shfl(lt, base + 2);
    float l3 = __shfl(lt, base + 3);
    int ei = 0; float lm = l0;
    if (l1 > lm) { lm = l1; ei = 1; }
    if (l2 > lm) { lm = l2; ei = 2; }
    if (l3 > lm) { lm = l3; ei = 3; }
    float s = expf(l0-lm)+expf(l1-lm)+expf(l2-lm)+expf(l3-lm);
    float w = 1.0f / s;                       // top-1 softmax prob
    int mt = bm*64 + wv*16 + lg*4 + r;
    size_t tbase = (size_t)((mt >> 10)*1029 + 5 + (mt & 1023))*64;
    #pragma unroll
    for (int j = 0; j < 4; ++j) {
      float d0 = acc[j][r], d1 = acc[4+j][r], d2 = acc[8+j][r], d3 = acc[12+j][r];
      float dsel = d0;
      dsel = (ei == 1) ? d1 : dsel;
      dsel = (ei == 2) ? d2 : dsel;
      dsel = (ei == 3) ? d3 : dsel;
      int col = j*16 + lr;
      float bev = sBe[ei*64 + col];
      float tv = h[tbase + col];              // exact fp32 t
      h[tbase + col] = tv + w * (dsel + bev);
    }
  }
}

// ---------------------------------------------------------------------------
// Kernel 3: out = (full . Wu^T) * gamma   M=65856, N=768, K=64
// One block per 64 tokens; loops 6 n-chunks of 128, staging Wu per chunk.
// ---------------------------------------------------------------------------
__global__ __launch_bounds__(256) void k3_up_gamma(
    const float* __restrict__ h, const float* __restrict__ Wu,
    const float* __restrict__ gamma, float* __restrict__ out)
{
  __shared__ uint4 AhS[512], AlS[512];       // full tile 64x64
  __shared__ uint4 BhS[1024], BlS[1024];     // Wu chunk 128x64
  char* Ah = (char*)AhS; char* Al = (char*)AlS;
  char* Bh = (char*)BhS; char* Bl = (char*)BlS;
  const int tid = threadIdx.x;
  const int bm  = blockIdx.x;
  const int wv = tid >> 6, l = tid & 63;
  const int lg = l >> 4, lr = l & 15;

  #pragma unroll
  for (int it = 0; it < 2; ++it) {
    int li = it*256 + tid;
    int row = li >> 3, kg = li & 7;
    const float* p = h + (size_t)(bm*64 + row)*64 + kg*8;
    float4 f0 = *(const float4*)p, f1 = *(const float4*)(p+4);
    split_store(Ah, Al, row, kg, f0, f1);
  }

  for (int c = 0; c < 6; ++c) {
    if (c) __syncthreads();                  // prev chunk's frag reads done
    #pragma unroll
    for (int it = 0; it < 4; ++it) {
      int li = it*256 + tid;
      int row = li >> 3, kg = li & 7;        // row 0..127 -> d = c*128+row
      const float* p = Wu + (size_t)(c*128 + row)*64 + kg*8;
      float4 f0 = *(const float4*)p, f1 = *(const float4*)(p+4);
      split_store(Bh, Bl, row, kg, f0, f1);
    }
    __syncthreads();

    f32x4 acc[8];
    #pragma unroll
    for (int i = 0; i < 8; ++i)
      #pragma unroll
      for (int j = 0; j < 4; ++j) acc[i][j] = 0.f;

    #pragma unroll
    for (int kc = 0; kc < 2; ++kc) {
      int kb = kc*64 + lg*16;
      bf16x8 ah = frag_ld(Ah, wv*16 + lr, kb);
      bf16x8 al = frag_ld(Al, wv*16 + lr, kb);
      #pragma unroll
      for (int nt = 0; nt < 8; ++nt) {
        bf16x8 bh = frag_ld(Bh, nt*16 + lr, kb);
        bf16x8 bl = frag_ld(Bl, nt*16 + lr, kb);
        acc[nt] = MFMA(ah, bh, acc[nt]);
        acc[nt] = MFMA(ah, bl, acc[nt]);
        acc[nt] = MFMA(al, bh, acc[nt]);
      }
    }
    #pragma unroll
    for (int nt = 0; nt < 8; ++nt) {
      int col = c*128 + nt*16 + lr;
      float gv = gamma[col];
      #pragma unroll
      for (int r = 0; r < 4; ++r) {
        int token = bm*64 + wv*16 + lg*4 + r;
        out[(size_t)token*768 + col] = acc[nt][r] * gv;
      }
    }
  }
}

extern "C" void kernel_launch(void* const* d_in, const int* in_sizes, int n_in,
                              void* d_out, int out_size, void* d_ws, size_t ws_size,
                              hipStream_t stream) {
  const float* x     = (const float*)d_in[0];
  const float* Wd    = (const float*)d_in[1];
  const float* Wg    = (const float*)d_in[2];
  const float* We    = (const float*)d_in[3];
  const float* be    = (const float*)d_in[4];
  const float* Wu    = (const float*)d_in[5];
  const float* gamma = (const float*)d_in[6];
  float* out = (float*)d_out;
  float* h   = (float*)d_ws;    // 65856*64 f32 = 16.9 MB scratch

  k1_proj_gelu<<<1029, 256, 0, stream>>>(x, Wd, h);
  k2_moe<<<1024, 256, 0, stream>>>(Wg, We, be, h);
  k3_up_gamma<<<1029, 256, 0, stream>>>(h, Wu, gamma, out);
}